// Round 3
// baseline (199.149 us; speedup 1.0000x reference)
//
#include <hip/hip_runtime.h>
#include <math.h>

#define S_N 2048
#define X_N 2048
#define G_N 2
#define F_N 3072

#define TM 128
#define TN 128
#define BK 32
#define KH (F_N / 2)      // 1536 per K-slice
#define ITERS (KH / BK)   // 48

typedef __bf16 bf16;
typedef __bf16 bf16x4 __attribute__((ext_vector_type(4)));
typedef __bf16 bf16x8 __attribute__((ext_vector_type(8)));
typedef float f32x4 __attribute__((ext_vector_type(4)));

// ---------------- P0a: const[g] = -0.5*F*log(2pi) - sum_f log(std[g,f]) ----
__global__ void k_const(const float* __restrict__ stdv, float* __restrict__ constg) {
  int g = blockIdx.x;
  int t = threadIdx.x;
  float s = 0.f;
  for (int f = t; f < F_N; f += 256) s += logf(stdv[g * F_N + f]);
  for (int o = 32; o; o >>= 1) s += __shfl_xor(s, o);
  __shared__ float red[4];
  int w = t >> 6, l = t & 63;
  if (l == 0) red[w] = s;
  __syncthreads();
  if (t == 0) {
    float tot = red[0] + red[1] + red[2] + red[3];
    constg[g] = -0.5f * (float)F_N * 1.8378770664093453f - tot;
  }
}

// ---------------- P0b: u = s/std_g (bf16) + A[g,s]=||u||^2 ; same for x->v,C
__global__ void k_prep(const float* __restrict__ samples, const float* __restrict__ xin,
                       const float* __restrict__ stdv,
                       bf16* __restrict__ U, bf16* __restrict__ V,
                       float* __restrict__ A, float* __restrict__ C) {
  int r = blockIdx.x;
  int t = threadIdx.x;
  bool isS = (r < S_N);
  const float* src = isS ? (samples + (size_t)r * F_N) : (xin + (size_t)(r - S_N) * F_N);
  float4 row[3];
#pragma unroll
  for (int j = 0; j < 3; ++j) row[j] = ((const float4*)src)[t + j * 256];

  __shared__ float red[4];
  int w = t >> 6, l = t & 63;

  for (int g = 0; g < G_N; ++g) {
    const float4* sd = (const float4*)(stdv + (size_t)g * F_N);
    bf16* dst = isS ? (U + ((size_t)g * S_N + r) * F_N)
                    : (V + ((size_t)g * X_N + (r - S_N)) * F_N);
    float acc = 0.f;
#pragma unroll
    for (int j = 0; j < 3; ++j) {
      float4 d = sd[t + j * 256];
      float u0 = row[j].x / d.x;
      float u1 = row[j].y / d.y;
      float u2 = row[j].z / d.z;
      float u3 = row[j].w / d.w;
      bf16x4 b;
      b[0] = (bf16)u0; b[1] = (bf16)u1; b[2] = (bf16)u2; b[3] = (bf16)u3;
      float f0 = (float)b[0], f1 = (float)b[1], f2 = (float)b[2], f3 = (float)b[3];
      acc += f0 * f0 + f1 * f1 + f2 * f2 + f3 * f3;
      ((bf16x4*)dst)[t + j * 256] = b;
    }
    for (int o = 32; o; o >>= 1) acc += __shfl_xor(acc, o);
    __syncthreads();
    if (l == 0) red[w] = acc;
    __syncthreads();
    if (t == 0) {
      float tot = red[0] + red[1] + red[2] + red[3];
      if (isS) A[(size_t)g * S_N + r] = tot;
      else     C[(size_t)g * X_N + (r - S_N)] = tot;
    }
  }
}

// ---------------- P1: parts[ks][g][s][x] = partial (u v^T) over K-slice ks ----
// 128x128 tile, split-K=2 -> 1024 blocks (4/CU = 4 barrier groups, 32 waves/CU).
// Depth-1 double-buffered LDS, one barrier/iter. Swizzle f(row)=(row>>1)&3.
__global__ __launch_bounds__(512, 8) void k_gemm(const bf16* __restrict__ U, const bf16* __restrict__ V,
                                                 float* __restrict__ parts) {
  __shared__ bf16 ldsA[2][TM * BK];
  __shared__ bf16 ldsB[2][TN * BK];

  int t = threadIdx.x;
  int z = blockIdx.z;          // 0..3: g = z>>1, ks = z&1
  int g = z >> 1, ks = z & 1;
  int bm = blockIdx.y * TM;
  int bn = blockIdx.x * TN;

  const bf16* Ub = U + ((size_t)g * S_N + bm) * F_N + ks * KH;
  const bf16* Vb = V + ((size_t)g * X_N + bn) * F_N + ks * KH;

  int wave = t >> 6, lane = t & 63;
  int wm = wave & 1;           // 64-row slice
  int wn = wave >> 1;          // 32-col slice
  int r = lane & 15, q = lane >> 4;
  int sq = q ^ ((r >> 1) & 3);  // read-side swizzled k-chunk (2-way banks = free)

  // Staging: thread t owns LDS slot t (16B). Slot (row, cc) holds global
  // chunk (row, cc ^ ((row>>1)&3)).
  int row0 = t >> 2, cc = t & 3;
  int gc0 = cc ^ ((row0 >> 1) & 3);
  const bf16* gA0 = Ub + (size_t)row0 * F_N + gc0 * 8;
  const bf16* gB0 = Vb + (size_t)row0 * F_N + gc0 * 8;

  f32x4 acc[4][2] = {};
  int abase = (wm * 64 + r) * BK + sq * 8;
  int bbase = (wn * 32 + r) * BK + sq * 8;

  // prologue: stage iter 0 into buf 0
  __builtin_amdgcn_global_load_lds((const __attribute__((address_space(1))) void*)gA0,
                                   (__attribute__((address_space(3))) void*)(&ldsA[0][t * 8]), 16, 0, 0);
  __builtin_amdgcn_global_load_lds((const __attribute__((address_space(1))) void*)gB0,
                                   (__attribute__((address_space(3))) void*)(&ldsB[0][t * 8]), 16, 0, 0);

  for (int it = 0; it < ITERS; ++it) {
    __syncthreads();  // drains vmcnt(0): buf[it&1] staged; prev compute done
    int b = it & 1;
    int nb = b ^ 1;
    int nk = (it + 1) * BK;  // last iter reads 16B past slice end: stays inside ws, never consumed
    __builtin_amdgcn_global_load_lds((const __attribute__((address_space(1))) void*)(gA0 + nk),
                                     (__attribute__((address_space(3))) void*)(&ldsA[nb][t * 8]), 16, 0, 0);
    __builtin_amdgcn_global_load_lds((const __attribute__((address_space(1))) void*)(gB0 + nk),
                                     (__attribute__((address_space(3))) void*)(&ldsB[nb][t * 8]), 16, 0, 0);

    bf16x8 af[4], bfr[2];
#pragma unroll
    for (int mi = 0; mi < 4; ++mi) af[mi] = *(const bf16x8*)(&ldsA[b][abase + mi * 16 * BK]);
#pragma unroll
    for (int ni = 0; ni < 2; ++ni) bfr[ni] = *(const bf16x8*)(&ldsB[b][bbase + ni * 16 * BK]);

#pragma unroll
    for (int mi = 0; mi < 4; ++mi)
#pragma unroll
      for (int ni = 0; ni < 2; ++ni)
        acc[mi][ni] = __builtin_amdgcn_mfma_f32_16x16x32_bf16(af[mi], bfr[ni], acc[mi][ni], 0, 0, 0);
  }

  // Epilogue: pure store of partial dot. C/D layout col=lane&15, row=q*4+reg.
  float* P = parts + ((size_t)(ks * G_N + g) * S_N + bm) * X_N + bn;
#pragma unroll
  for (int mi = 0; mi < 4; ++mi) {
#pragma unroll
    for (int i = 0; i < 4; ++i) {
      int rowl = wm * 64 + mi * 16 + q * 4 + i;
      float* orow = P + (size_t)rowl * X_N + wn * 32;
#pragma unroll
      for (int ni = 0; ni < 2; ++ni)
        orow[ni * 16 + r] = acc[mi][ni][i];
    }
  }
}

// ---------------- P2: out[s] = LSE over (g,x) of (dot - 0.5*(A+C) + const[g]) - log(X*G)
__global__ void k_lse(const float* __restrict__ parts,
                      const float* __restrict__ A, const float* __restrict__ C,
                      const float* __restrict__ constg, float* __restrict__ out) {
  int s = blockIdx.x, t = threadIdx.x;
  float c0 = constg[0] - 0.5f * A[s];
  float c1 = constg[1] - 0.5f * A[S_N + s];
  const float4* p00 = (const float4*)(parts + (size_t)(0 * G_N + 0) * S_N * X_N + (size_t)s * X_N);
  const float4* p01 = (const float4*)(parts + (size_t)(0 * G_N + 1) * S_N * X_N + (size_t)s * X_N);
  const float4* p10 = (const float4*)(parts + (size_t)(1 * G_N + 0) * S_N * X_N + (size_t)s * X_N);
  const float4* p11 = (const float4*)(parts + (size_t)(1 * G_N + 1) * S_N * X_N + (size_t)s * X_N);
  const float4* Cg0 = (const float4*)(C);
  const float4* Cg1 = (const float4*)(C + X_N);

  float4 v[4], ca[4];
  {
    float4 a0 = p00[t], b0 = p10[t];
    float4 a1 = p00[t + 256], b1 = p10[t + 256];
    float4 a2 = p01[t], b2 = p11[t];
    float4 a3 = p01[t + 256], b3 = p11[t + 256];
    ca[0] = Cg0[t]; ca[1] = Cg0[t + 256]; ca[2] = Cg1[t]; ca[3] = Cg1[t + 256];
    v[0].x = a0.x + b0.x + c0 - 0.5f * ca[0].x; v[0].y = a0.y + b0.y + c0 - 0.5f * ca[0].y;
    v[0].z = a0.z + b0.z + c0 - 0.5f * ca[0].z; v[0].w = a0.w + b0.w + c0 - 0.5f * ca[0].w;
    v[1].x = a1.x + b1.x + c0 - 0.5f * ca[1].x; v[1].y = a1.y + b1.y + c0 - 0.5f * ca[1].y;
    v[1].z = a1.z + b1.z + c0 - 0.5f * ca[1].z; v[1].w = a1.w + b1.w + c0 - 0.5f * ca[1].w;
    v[2].x = a2.x + b2.x + c1 - 0.5f * ca[2].x; v[2].y = a2.y + b2.y + c1 - 0.5f * ca[2].y;
    v[2].z = a2.z + b2.z + c1 - 0.5f * ca[2].z; v[2].w = a2.w + b2.w + c1 - 0.5f * ca[2].w;
    v[3].x = a3.x + b3.x + c1 - 0.5f * ca[3].x; v[3].y = a3.y + b3.y + c1 - 0.5f * ca[3].y;
    v[3].z = a3.z + b3.z + c1 - 0.5f * ca[3].z; v[3].w = a3.w + b3.w + c1 - 0.5f * ca[3].w;
  }

  float m = v[0].x;
#pragma unroll
  for (int j = 0; j < 4; ++j) {
    m = fmaxf(m, v[j].x); m = fmaxf(m, v[j].y);
    m = fmaxf(m, v[j].z); m = fmaxf(m, v[j].w);
  }
  for (int o = 32; o; o >>= 1) m = fmaxf(m, __shfl_xor(m, o));
  __shared__ float redm[4];
  __shared__ float reds[4];
  int w = t >> 6, l = t & 63;
  if (l == 0) redm[w] = m;
  __syncthreads();
  m = fmaxf(fmaxf(redm[0], redm[1]), fmaxf(redm[2], redm[3]));

  float sum = 0.f;
#pragma unroll
  for (int j = 0; j < 4; ++j) {
    sum += expf(v[j].x - m) + expf(v[j].y - m) + expf(v[j].z - m) + expf(v[j].w - m);
  }
  for (int o = 32; o; o >>= 1) sum += __shfl_xor(sum, o);
  if (l == 0) reds[w] = sum;
  __syncthreads();
  if (t == 0) {
    float tot = reds[0] + reds[1] + reds[2] + reds[3];
    out[s] = m + logf(tot) - 8.317766166719343f;  // log(4096)
  }
}

extern "C" void kernel_launch(void* const* d_in, const int* in_sizes, int n_in,
                              void* d_out, int out_size, void* d_ws, size_t ws_size,
                              hipStream_t stream) {
  const float* samples = (const float*)d_in[0];  // [S, F] fp32
  const float* xin     = (const float*)d_in[1];  // [X, F] fp32
  const float* stdv    = (const float*)d_in[2];  // [G, F] fp32
  float* out = (float*)d_out;                    // [S] fp32

  char* ws = (char*)d_ws;
  size_t off = 0;
  bf16* U = (bf16*)(ws + off);        off += (size_t)G_N * S_N * F_N * 2;          // 25.2 MB
  bf16* V = (bf16*)(ws + off);        off += (size_t)G_N * X_N * F_N * 2;          // 25.2 MB
  float* parts = (float*)(ws + off);  off += (size_t)2 * G_N * S_N * X_N * 4;      // 67.1 MB
  float* A = (float*)(ws + off);      off += (size_t)G_N * S_N * 4;
  float* C = (float*)(ws + off);      off += (size_t)G_N * X_N * 4;
  float* constg = (float*)(ws + off); off += 256;

  k_const<<<dim3(G_N), dim3(256), 0, stream>>>(stdv, constg);
  k_prep<<<dim3(S_N + X_N), dim3(256), 0, stream>>>(samples, xin, stdv, U, V, A, C);
  k_gemm<<<dim3(X_N / TN, S_N / TM, 2 * G_N), dim3(512), 0, stream>>>(U, V, parts);
  k_lse<<<dim3(S_N), dim3(256), 0, stream>>>(parts, A, C, constg, out);
}